// Round 2
// baseline (398.068 us; speedup 1.0000x reference)
//
#include <hip/hip_runtime.h>
#include <hip/hip_bf16.h>
#include <math.h>

#define N_T    16384
#define N_ROWS 2048
#define M_FFT  8192
#define TW_N   4096
#define K_LO   410
#define K_HI   1365
#define TILE   4096

__device__ __forceinline__ int rev13(int k) { return (int)(__brev((unsigned)k) >> 19); }

__global__ void init_tw_kernel(float2* __restrict__ tw) {
    int m = blockIdx.x * blockDim.x + threadIdx.x;
    if (m < TW_N) {
        float th = (float)(M_PI) * (float)m / (float)TW_N;
        float s, c;
        sincosf(th, &s, &c);
        tw[m] = make_float2(c, -s);
    }
}

// One workgroup per (row, array). 8192-pt complex DIF FFT in LDS, band argmax.
__global__ __launch_bounds__(256) void fft_kernel(const float* __restrict__ pred,
                                                  const float* __restrict__ targ,
                                                  const float2* __restrict__ tw,
                                                  float* __restrict__ fout) {
    extern __shared__ float2 z[];  // 8192 complex = 64 KB
    int wg  = blockIdx.x;
    int row = wg >> 1, arr = wg & 1;
    const float* x = (arr == 0 ? pred : targ) + (size_t)row * N_T;
    int tid = threadIdx.x;

    // load row as packed complex (even/odd interleave == raw float2 view)
    const float4* x4 = (const float4*)x;
    float4* z4 = (float4*)z;
#pragma unroll
    for (int q = 0; q < 16; ++q) z4[tid + 256 * q] = x4[tid + 256 * q];
    __syncthreads();

    // 13 radix-2 DIF stages; output in bit-reversed order
    for (int s = 0; s < 13; ++s) {
        int log2h = 12 - s;
        int h = 1 << log2h;
#pragma unroll
        for (int m = 0; m < 16; ++m) {
            int b  = tid + 256 * m;
            int j  = b & (h - 1);
            int i0 = ((b >> log2h) << (log2h + 1)) | j;
            float2 a = z[i0];
            float2 c = z[i0 + h];
            float2 w = tw[j << s];
            z[i0] = make_float2(a.x + c.x, a.y + c.y);
            float dx = a.x - c.x, dy = a.y - c.y;
            z[i0 + h] = make_float2(dx * w.x - dy * w.y, dx * w.y + dy * w.x);
        }
        __syncthreads();
    }

    // combine to rfft bins in band, track argmax (tie -> lowest k)
    float bestp = -1.0f;
    int bestk = 1 << 30;
    for (int k = K_LO + tid; k <= K_HI; k += 256) {
        float2 A = z[rev13(k)];
        float2 B = z[rev13(M_FFT - k)];
        float Er = 0.5f * (A.x + B.x), Ei = 0.5f * (A.y - B.y);
        float Or = 0.5f * (A.y + B.y), Oi = 0.5f * (B.x - A.x);
        float th = (float)(M_PI) * (float)k / 8192.0f;
        float sn, cs;
        sincosf(th, &sn, &cs);
        float Xr = Er + cs * Or + sn * Oi;
        float Xi = Ei + cs * Oi - sn * Or;
        float p = Xr * Xr + Xi * Xi;
        if (p > bestp) { bestp = p; bestk = k; }
    }
    for (int off = 1; off < 64; off <<= 1) {
        float op = __shfl_xor(bestp, off);
        int   ok = __shfl_xor(bestk, off);
        if (op > bestp || (op == bestp && ok < bestk)) { bestp = op; bestk = ok; }
    }
    __syncthreads();  // all z reads done; reuse z[0..3] for cross-wave reduce
    if ((tid & 63) == 0) z[tid >> 6] = make_float2(bestp, (float)bestk);
    __syncthreads();
    if (tid == 0) {
        for (int wv = 0; wv < 4; ++wv) {
            float2 rr = z[wv];
            int ok = (int)rr.y;
            if (rr.x > bestp || (rr.x == bestp && ok < bestk)) { bestp = rr.x; bestk = ok; }
        }
        fout[arr * N_ROWS + row] = (float)bestk * (30.0f / 16384.0f);
    }
}

// One workgroup per row: pearson sums, derivative cos-sim sums, peak counts/sums.
__global__ __launch_bounds__(256) void stats_kernel(const float* __restrict__ pred,
                                                    const float* __restrict__ targ,
                                                    float* __restrict__ wpear,
                                                    float* __restrict__ wderiv,
                                                    float* __restrict__ wpeak) {
    __shared__ float spb[TILE + 8], stb[TILE + 8];
    __shared__ float red[4][17];
    float* sp = spb + 4;
    float* st = stb + 4;
    int row = blockIdx.x, tid = threadIdx.x;
    const float* p = pred + (size_t)row * N_T;
    const float* t = targ + (size_t)row * N_T;

    float acc[17];
#pragma unroll
    for (int q = 0; q < 17; ++q) acc[q] = 0.0f;

    for (int tile = 0; tile < N_T / TILE; ++tile) {
        int base = tile * TILE;
        __syncthreads();  // protect LDS from previous-iteration readers
        const float4* p4 = (const float4*)(p + base);
        const float4* t4 = (const float4*)(t + base);
        float4* sp4 = (float4*)sp;
        float4* st4 = (float4*)st;
#pragma unroll
        for (int q = 0; q < 4; ++q) {
            sp4[tid + 256 * q] = p4[tid + 256 * q];
            st4[tid + 256 * q] = t4[tid + 256 * q];
        }
        if (tid == 0 && base > 0) { sp[-1] = p[base - 1]; sp[-2] = p[base - 2]; }
        if (tid == 1 && base > 0) { st[-1] = t[base - 1]; st[-2] = t[base - 2]; }
        if (tid == 2 && base + TILE < N_T) { sp[TILE] = p[base + TILE]; sp[TILE + 1] = p[base + TILE + 1]; }
        if (tid == 3 && base + TILE < N_T) { st[TILE] = t[base + TILE]; st[TILE + 1] = t[base + TILE + 1]; }
        __syncthreads();

        for (int m = 0; m < 16; ++m) {
            int j = tid + 256 * m;
            int i = base + j;
            float p0 = sp[j], t0 = st[j];
            acc[0] += p0; acc[1] += p0 * p0;
            acc[2] += t0; acc[3] += t0 * t0;
            acc[4] += p0 * t0;
            float g1p, g1t, g2p, g2t;
            if (i >= 2 && i <= N_T - 3) {
                float pm2 = sp[j - 2], pm1 = sp[j - 1], pp1 = sp[j + 1], pp2 = sp[j + 2];
                float tm2 = st[j - 2], tm1 = st[j - 1], tp1 = st[j + 1], tp2 = st[j + 2];
                g1p = 0.5f * (pp1 - pm1); g1t = 0.5f * (tp1 - tm1);
                g2p = 0.5f * (0.5f * (pp2 - p0) - 0.5f * (p0 - pm2));
                g2t = 0.5f * (0.5f * (tp2 - t0) - 0.5f * (t0 - tm2));
            } else if (i == 0) {
                float x1 = sp[j + 1], x2 = sp[j + 2];
                g1p = x1 - p0;              g2p = 0.5f * (x2 - p0) - (x1 - p0);
                float y1 = st[j + 1], y2 = st[j + 2];
                g1t = y1 - t0;              g2t = 0.5f * (y2 - t0) - (y1 - t0);
            } else if (i == 1) {
                float x0 = sp[j - 1], x2 = sp[j + 1], x3 = sp[j + 2];
                g1p = 0.5f * (x2 - x0);     g2p = 0.5f * (0.5f * (x3 - p0) - (p0 - x0));
                float y0 = st[j - 1], y2 = st[j + 1], y3 = st[j + 2];
                g1t = 0.5f * (y2 - y0);     g2t = 0.5f * (0.5f * (y3 - t0) - (t0 - y0));
            } else if (i == N_T - 2) {
                float xm2 = sp[j - 2], xm1 = sp[j - 1], xp1 = sp[j + 1];
                g1p = 0.5f * (xp1 - xm1);   g2p = 0.5f * ((xp1 - p0) - 0.5f * (p0 - xm2));
                float ym2 = st[j - 2], ym1 = st[j - 1], yp1 = st[j + 1];
                g1t = 0.5f * (yp1 - ym1);   g2t = 0.5f * ((yp1 - t0) - 0.5f * (t0 - ym2));
            } else {  // i == N_T-1
                float xm2 = sp[j - 2], xm1 = sp[j - 1];
                g1p = p0 - xm1;             g2p = (p0 - xm1) - 0.5f * (p0 - xm2);
                float ym2 = st[j - 2], ym1 = st[j - 1];
                g1t = t0 - ym1;             g2t = (t0 - ym1) - 0.5f * (t0 - ym2);
            }
            acc[5] += g1p * g1t; acc[6] += g1p * g1p; acc[7] += g1t * g1t;
            acc[8] += g2p * g2t; acc[9] += g2p * g2p; acc[10] += g2t * g2t;
            if (i >= 1 && i <= N_T - 2) {
                float pm1 = sp[j - 1], pp1 = sp[j + 1];
                float tm1 = st[j - 1], tp1 = st[j + 1];
                bool mx  = (p0 > pm1) && (p0 > pp1);
                bool mn  = (p0 < pm1) && (p0 < pp1);
                bool mxt = (t0 > tm1) && (t0 > tp1);
                bool mnt = (t0 < tm1) && (t0 < tp1);
                acc[11] += mx ? 1.0f : 0.0f;
                acc[12] += mn ? 1.0f : 0.0f;
                acc[13] += mxt ? 1.0f : 0.0f;
                acc[14] += mnt ? 1.0f : 0.0f;
                acc[15] += mx ? p0 : 0.0f;
                acc[16] += mn ? p0 : 0.0f;
            }
        }
    }

    int lane = tid & 63, wv = tid >> 6;
#pragma unroll
    for (int q = 0; q < 17; ++q) {
        float v = acc[q];
        for (int off = 1; off < 64; off <<= 1) v += __shfl_xor(v, off);
        if (lane == 0) red[wv][q] = v;
    }
    __syncthreads();
    if (tid == 0) {
        float a[17];
#pragma unroll
        for (int q = 0; q < 17; ++q) a[q] = red[0][q] + red[1][q] + red[2][q] + red[3][q];
        const float Nf = (float)N_T;
        float cov = a[4] - a[0] * a[2] / Nf;
        float vp  = a[1] - a[0] * a[0] / Nf;
        float vt  = a[3] - a[2] * a[2] / Nf;
        float r   = cov / sqrtf(vp * vt);
        float c1  = a[5] / sqrtf(a[6] * a[7]);
        float c2  = a[8] / sqrtf(a[9] * a[10]);
        float cntd  = fabsf(a[13] - a[11]);
        float ncntd = fabsf(a[14] - a[12]);
        float vald  = fabsf(1.0f - a[15] / a[11]);
        float nvald = fabsf(1.0f - a[16] / a[12]);
        wpear[row]  = 1.0f - r;
        wderiv[row] = c1 + c2;
        wpeak[row]  = 0.5f * (cntd + ncntd + vald + nvald);
    }
}

__global__ __launch_bounds__(256) void reduce_kernel(const float* __restrict__ wpear,
                                                     const float* __restrict__ wderiv,
                                                     const float* __restrict__ wpeak,
                                                     const float* __restrict__ fout,
                                                     float* __restrict__ out) {
    __shared__ float red[4][3];
    int tid = threadIdx.x;
    float s1 = 0.0f, s2 = 0.0f, s3 = 0.0f;
    for (int r = tid; r < N_ROWS; r += 256) {
        s1 += wpear[r];
        s2 += wderiv[r];
        s3 += wpeak[r] + fabsf(fout[N_ROWS + r] - fout[r]);
    }
    int lane = tid & 63, wv = tid >> 6;
    for (int off = 1; off < 64; off <<= 1) {
        s1 += __shfl_xor(s1, off);
        s2 += __shfl_xor(s2, off);
        s3 += __shfl_xor(s3, off);
    }
    if (lane == 0) { red[wv][0] = s1; red[wv][1] = s2; red[wv][2] = s3; }
    __syncthreads();
    if (tid == 0) {
        float a = 0.0f, b = 0.0f, c = 0.0f;
        for (int w = 0; w < 4; ++w) { a += red[w][0]; b += red[w][1]; c += red[w][2]; }
        const float Nf = (float)N_ROWS;
        float res = a / Nf + c / Nf + (2.0f - b / Nf);
        out[0] = res;  // reference output dtype is float32, NOT bf16
    }
}

extern "C" void kernel_launch(void* const* d_in, const int* in_sizes, int n_in,
                              void* d_out, int out_size, void* d_ws, size_t ws_size,
                              hipStream_t stream) {
    const float* pred = (const float*)d_in[0];
    const float* targ = (const float*)d_in[1];
    float* ws = (float*)d_ws;
    float2* tw   = (float2*)ws;          // 4096 float2 = 8192 floats
    float* wpear = ws + 8192;            // 2048
    float* wderiv = ws + 8192 + 2048;    // 2048
    float* wpeak = ws + 8192 + 4096;     // 2048
    float* fout  = ws + 8192 + 6144;     // 4096 (pred freqs, then targ freqs)

    init_tw_kernel<<<16, 256, 0, stream>>>(tw);
    stats_kernel<<<N_ROWS, 256, 0, stream>>>(pred, targ, wpear, wderiv, wpeak);
    fft_kernel<<<2 * N_ROWS, 256, 65536, stream>>>(pred, targ, tw, fout);
    reduce_kernel<<<1, 256, 0, stream>>>(wpear, wderiv, wpeak, fout, (float*)d_out);
}

// Round 3
// 204.109 us; speedup vs baseline: 1.9503x; 1.9503x over previous
//
#include <hip/hip_runtime.h>
#include <hip/hip_bf16.h>
#include <math.h>

#define N_T    16384
#define N_ROWS 2048
#define M_FFT  8192
#define K_LO   410
#define K_HI   1365
#define TILE   4096

__device__ __forceinline__ int rev13(int k) { return (int)(__brev((unsigned)k) >> 19); }
__device__ __forceinline__ float2 cmul(float2 a, float2 b) {
    return make_float2(a.x * b.x - a.y * b.y, a.x * b.y + a.y * b.x);
}
__device__ __forceinline__ int swz(int i) { return i ^ (((i >> 8) & 7) << 1); }

// One workgroup per (row, array). 8192-pt complex FFT: 5 register stages,
// swizzled LDS transpose, 5 register stages, 3 shfl stages, band argmax.
__global__ __launch_bounds__(256) void fft_kernel(const float* __restrict__ pred,
                                                  const float* __restrict__ targ,
                                                  float* __restrict__ fout) {
    extern __shared__ float2 z[];  // 8192 float2 = 64 KB
    const int wg = blockIdx.x;
    const int row = wg >> 1, arr = wg & 1;
    const float2* __restrict__ x = (const float2*)((arr ? targ : pred) + (size_t)row * N_T);
    const int t = threadIdx.x;

    float2 r[32];
#pragma unroll
    for (int m = 0; m < 32; ++m) r[m] = x[t + 256 * m];

    // ---- phase 1: DIF stages h = 4096,2048,1024,512,256 (register-internal) ----
#pragma unroll
    for (int p = 0; p < 5; ++p) {
        const int d = 16 >> p;  // partner offset in register index; h = 256*d
        float s0, c0, ss, cs;
        __sincosf((float)M_PI * (float)t / (float)(256 * d), &s0, &c0);
        __sincosf((float)M_PI / (float)d, &ss, &cs);
        const float2 wbase = make_float2(c0, -s0);
        const float2 wstep = make_float2(cs, -ss);
        float2 cw = wbase;
#pragma unroll
        for (int m = 0; m < 32; ++m) {
            if ((m & d) == 0) {
                float2 a = r[m], bq = r[m + d];
                r[m] = make_float2(a.x + bq.x, a.y + bq.y);
                float2 df = make_float2(a.x - bq.x, a.y - bq.y);
                r[m + d] = cmul(df, cw);
                if ((m & (d - 1)) == (d - 1)) cw = wbase;   // group wrap
                else cw = cmul(cw, wstep);
            }
        }
    }

    // ---- transpose via LDS: (t + 256m) -> (256b + c + 8w), b=t>>3, c=t&7 ----
#pragma unroll
    for (int m = 0; m < 32; ++m) {
        int i = t + 256 * m;
        z[swz(i)] = r[m];
    }
    __syncthreads();
    const int bb = t >> 3, cc = t & 7;
#pragma unroll
    for (int w = 0; w < 32; ++w) {
        int i = 256 * bb + cc + 8 * w;
        r[w] = z[swz(i)];
    }

    // ---- phase 2: DIF stages h = 128,64,32,16,8 (register-internal) ----
#pragma unroll
    for (int p = 0; p < 5; ++p) {
        const int d = 16 >> p;  // h = 8*d
        float s0, c0, ss, cs;
        __sincosf((float)M_PI * (float)cc / (float)(8 * d), &s0, &c0);
        __sincosf((float)M_PI / (float)d, &ss, &cs);
        const float2 wbase = make_float2(c0, -s0);
        const float2 wstep = make_float2(cs, -ss);
        float2 cw = wbase;
#pragma unroll
        for (int w = 0; w < 32; ++w) {
            if ((w & d) == 0) {
                float2 a = r[w], bq = r[w + d];
                r[w] = make_float2(a.x + bq.x, a.y + bq.y);
                float2 df = make_float2(a.x - bq.x, a.y - bq.y);
                r[w + d] = cmul(df, cw);
                if ((w & (d - 1)) == (d - 1)) cw = wbase;
                else cw = cmul(cw, wstep);
            }
        }
    }

    // ---- phase 3: DIF stages h = 4,2,1 via shfl_xor across c ----
    {   // h=4: twiddle e^{-i*pi*(c&3)/4} on upper half (c&4)
        float s1, c1;
        __sincosf((float)M_PI * (float)(cc & 3) * 0.25f, &s1, &c1);
        const float2 w4 = make_float2(c1, -s1);
        const bool up = (cc & 4) != 0;
#pragma unroll
        for (int w = 0; w < 32; ++w) {
            float ox = __shfl_xor(r[w].x, 4);
            float oy = __shfl_xor(r[w].y, 4);
            if (!up) { r[w].x += ox; r[w].y += oy; }
            else {
                float2 df = make_float2(ox - r[w].x, oy - r[w].y);
                r[w] = cmul(df, w4);
            }
        }
    }
    {   // h=2: twiddle {1,-i} by c&1 on upper half (c&2)
        const bool up = (cc & 2) != 0;
        const bool j1 = (cc & 1) != 0;
#pragma unroll
        for (int w = 0; w < 32; ++w) {
            float ox = __shfl_xor(r[w].x, 2);
            float oy = __shfl_xor(r[w].y, 2);
            if (!up) { r[w].x += ox; r[w].y += oy; }
            else {
                float dx = ox - r[w].x, dy = oy - r[w].y;
                r[w] = j1 ? make_float2(dy, -dx) : make_float2(dx, dy);
            }
        }
    }
    {   // h=1: no twiddle
        const bool up = (cc & 1) != 0;
#pragma unroll
        for (int w = 0; w < 32; ++w) {
            float ox = __shfl_xor(r[w].x, 1);
            float oy = __shfl_xor(r[w].y, 1);
            if (!up) { r[w].x += ox; r[w].y += oy; }
            else { r[w] = make_float2(ox - r[w].x, oy - r[w].y); }
        }
    }

    // ---- final store (bit-reversed-content array in natural position order) ----
    __syncthreads();  // all transpose reads done before overwrite
#pragma unroll
    for (int w = 0; w < 32; ++w) {
        int i = 256 * bb + cc + 8 * w;
        z[swz(i)] = r[w];
    }
    __syncthreads();

    // ---- combine to rfft bins in band, argmax (tie -> lowest k) ----
    float bestp = -1.0f;
    int bestk = 1 << 30;
    for (int k = K_LO + t; k <= K_HI; k += 256) {
        float2 A = z[swz(rev13(k))];
        float2 B = z[swz(rev13(M_FFT - k))];
        float Er = 0.5f * (A.x + B.x), Ei = 0.5f * (A.y - B.y);
        float Or = 0.5f * (A.y + B.y), Oi = 0.5f * (B.x - A.x);
        float th = (float)(M_PI) * (float)k / 8192.0f;
        float sn, cs;
        sincosf(th, &sn, &cs);
        float Xr = Er + cs * Or + sn * Oi;
        float Xi = Ei + cs * Oi - sn * Or;
        float p = Xr * Xr + Xi * Xi;
        if (p > bestp) { bestp = p; bestk = k; }
    }
    for (int off = 1; off < 64; off <<= 1) {
        float op = __shfl_xor(bestp, off);
        int   ok = __shfl_xor(bestk, off);
        if (op > bestp || (op == bestp && ok < bestk)) { bestp = op; bestk = ok; }
    }
    __syncthreads();  // all z reads done; reuse z[0..3] for cross-wave reduce
    if ((t & 63) == 0) z[t >> 6] = make_float2(bestp, (float)bestk);
    __syncthreads();
    if (t == 0) {
        for (int wv = 0; wv < 4; ++wv) {
            float2 rr = z[wv];
            int ok = (int)rr.y;
            if (rr.x > bestp || (rr.x == bestp && ok < bestk)) { bestp = rr.x; bestk = ok; }
        }
        fout[arr * N_ROWS + row] = (float)bestk * (30.0f / 16384.0f);
    }
}

// One workgroup per row: pearson sums, derivative cos-sim sums, peak counts/sums.
__global__ __launch_bounds__(256) void stats_kernel(const float* __restrict__ pred,
                                                    const float* __restrict__ targ,
                                                    float* __restrict__ wpear,
                                                    float* __restrict__ wderiv,
                                                    float* __restrict__ wpeak) {
    __shared__ float spb[TILE + 8], stb[TILE + 8];
    __shared__ float red[4][17];
    float* sp = spb + 4;
    float* st = stb + 4;
    int row = blockIdx.x, tid = threadIdx.x;
    const float* p = pred + (size_t)row * N_T;
    const float* t = targ + (size_t)row * N_T;

    float acc[17];
#pragma unroll
    for (int q = 0; q < 17; ++q) acc[q] = 0.0f;

    for (int tile = 0; tile < N_T / TILE; ++tile) {
        int base = tile * TILE;
        __syncthreads();  // protect LDS from previous-iteration readers
        const float4* p4 = (const float4*)(p + base);
        const float4* t4 = (const float4*)(t + base);
        float4* sp4 = (float4*)sp;
        float4* st4 = (float4*)st;
#pragma unroll
        for (int q = 0; q < 4; ++q) {
            sp4[tid + 256 * q] = p4[tid + 256 * q];
            st4[tid + 256 * q] = t4[tid + 256 * q];
        }
        if (tid == 0 && base > 0) { sp[-1] = p[base - 1]; sp[-2] = p[base - 2]; }
        if (tid == 1 && base > 0) { st[-1] = t[base - 1]; st[-2] = t[base - 2]; }
        if (tid == 2 && base + TILE < N_T) { sp[TILE] = p[base + TILE]; sp[TILE + 1] = p[base + TILE + 1]; }
        if (tid == 3 && base + TILE < N_T) { st[TILE] = t[base + TILE]; st[TILE + 1] = t[base + TILE + 1]; }
        __syncthreads();

        for (int m = 0; m < 16; ++m) {
            int j = tid + 256 * m;
            int i = base + j;
            float p0 = sp[j], t0 = st[j];
            acc[0] += p0; acc[1] += p0 * p0;
            acc[2] += t0; acc[3] += t0 * t0;
            acc[4] += p0 * t0;
            float g1p, g1t, g2p, g2t;
            if (i >= 2 && i <= N_T - 3) {
                float pm2 = sp[j - 2], pm1 = sp[j - 1], pp1 = sp[j + 1], pp2 = sp[j + 2];
                float tm2 = st[j - 2], tm1 = st[j - 1], tp1 = st[j + 1], tp2 = st[j + 2];
                g1p = 0.5f * (pp1 - pm1); g1t = 0.5f * (tp1 - tm1);
                g2p = 0.5f * (0.5f * (pp2 - p0) - 0.5f * (p0 - pm2));
                g2t = 0.5f * (0.5f * (tp2 - t0) - 0.5f * (t0 - tm2));
            } else if (i == 0) {
                float x1 = sp[j + 1], x2 = sp[j + 2];
                g1p = x1 - p0;              g2p = 0.5f * (x2 - p0) - (x1 - p0);
                float y1 = st[j + 1], y2 = st[j + 2];
                g1t = y1 - t0;              g2t = 0.5f * (y2 - t0) - (y1 - t0);
            } else if (i == 1) {
                float x0 = sp[j - 1], x2 = sp[j + 1], x3 = sp[j + 2];
                g1p = 0.5f * (x2 - x0);     g2p = 0.5f * (0.5f * (x3 - p0) - (p0 - x0));
                float y0 = st[j - 1], y2 = st[j + 1], y3 = st[j + 2];
                g1t = 0.5f * (y2 - y0);     g2t = 0.5f * (0.5f * (y3 - t0) - (t0 - y0));
            } else if (i == N_T - 2) {
                float xm2 = sp[j - 2], xm1 = sp[j - 1], xp1 = sp[j + 1];
                g1p = 0.5f * (xp1 - xm1);   g2p = 0.5f * ((xp1 - p0) - 0.5f * (p0 - xm2));
                float ym2 = st[j - 2], ym1 = st[j - 1], yp1 = st[j + 1];
                g1t = 0.5f * (yp1 - ym1);   g2t = 0.5f * ((yp1 - t0) - 0.5f * (t0 - ym2));
            } else {  // i == N_T-1
                float xm2 = sp[j - 2], xm1 = sp[j - 1];
                g1p = p0 - xm1;             g2p = (p0 - xm1) - 0.5f * (p0 - xm2);
                float ym2 = st[j - 2], ym1 = st[j - 1];
                g1t = t0 - ym1;             g2t = (t0 - ym1) - 0.5f * (t0 - ym2);
            }
            acc[5] += g1p * g1t; acc[6] += g1p * g1p; acc[7] += g1t * g1t;
            acc[8] += g2p * g2t; acc[9] += g2p * g2p; acc[10] += g2t * g2t;
            if (i >= 1 && i <= N_T - 2) {
                float pm1 = sp[j - 1], pp1 = sp[j + 1];
                float tm1 = st[j - 1], tp1 = st[j + 1];
                bool mx  = (p0 > pm1) && (p0 > pp1);
                bool mn  = (p0 < pm1) && (p0 < pp1);
                bool mxt = (t0 > tm1) && (t0 > tp1);
                bool mnt = (t0 < tm1) && (t0 < tp1);
                acc[11] += mx ? 1.0f : 0.0f;
                acc[12] += mn ? 1.0f : 0.0f;
                acc[13] += mxt ? 1.0f : 0.0f;
                acc[14] += mnt ? 1.0f : 0.0f;
                acc[15] += mx ? p0 : 0.0f;
                acc[16] += mn ? p0 : 0.0f;
            }
        }
    }

    int lane = tid & 63, wv = tid >> 6;
#pragma unroll
    for (int q = 0; q < 17; ++q) {
        float v = acc[q];
        for (int off = 1; off < 64; off <<= 1) v += __shfl_xor(v, off);
        if (lane == 0) red[wv][q] = v;
    }
    __syncthreads();
    if (tid == 0) {
        float a[17];
#pragma unroll
        for (int q = 0; q < 17; ++q) a[q] = red[0][q] + red[1][q] + red[2][q] + red[3][q];
        const float Nf = (float)N_T;
        float cov = a[4] - a[0] * a[2] / Nf;
        float vp  = a[1] - a[0] * a[0] / Nf;
        float vt  = a[3] - a[2] * a[2] / Nf;
        float r   = cov / sqrtf(vp * vt);
        float c1  = a[5] / sqrtf(a[6] * a[7]);
        float c2  = a[8] / sqrtf(a[9] * a[10]);
        float cntd  = fabsf(a[13] - a[11]);
        float ncntd = fabsf(a[14] - a[12]);
        float vald  = fabsf(1.0f - a[15] / a[11]);
        float nvald = fabsf(1.0f - a[16] / a[12]);
        wpear[row]  = 1.0f - r;
        wderiv[row] = c1 + c2;
        wpeak[row]  = 0.5f * (cntd + ncntd + vald + nvald);
    }
}

__global__ __launch_bounds__(256) void reduce_kernel(const float* __restrict__ wpear,
                                                     const float* __restrict__ wderiv,
                                                     const float* __restrict__ wpeak,
                                                     const float* __restrict__ fout,
                                                     float* __restrict__ out) {
    __shared__ float red[4][3];
    int tid = threadIdx.x;
    float s1 = 0.0f, s2 = 0.0f, s3 = 0.0f;
    for (int r = tid; r < N_ROWS; r += 256) {
        s1 += wpear[r];
        s2 += wderiv[r];
        s3 += wpeak[r] + fabsf(fout[N_ROWS + r] - fout[r]);
    }
    int lane = tid & 63, wv = tid >> 6;
    for (int off = 1; off < 64; off <<= 1) {
        s1 += __shfl_xor(s1, off);
        s2 += __shfl_xor(s2, off);
        s3 += __shfl_xor(s3, off);
    }
    if (lane == 0) { red[wv][0] = s1; red[wv][1] = s2; red[wv][2] = s3; }
    __syncthreads();
    if (tid == 0) {
        float a = 0.0f, b = 0.0f, c = 0.0f;
        for (int w = 0; w < 4; ++w) { a += red[w][0]; b += red[w][1]; c += red[w][2]; }
        const float Nf = (float)N_ROWS;
        float res = a / Nf + c / Nf + (2.0f - b / Nf);
        out[0] = res;  // reference output dtype is float32
    }
}

extern "C" void kernel_launch(void* const* d_in, const int* in_sizes, int n_in,
                              void* d_out, int out_size, void* d_ws, size_t ws_size,
                              hipStream_t stream) {
    const float* pred = (const float*)d_in[0];
    const float* targ = (const float*)d_in[1];
    float* ws = (float*)d_ws;
    float* wpear  = ws;             // 2048
    float* wderiv = ws + 2048;      // 2048
    float* wpeak  = ws + 4096;      // 2048
    float* fout   = ws + 6144;      // 4096 (pred freqs, then targ freqs)

    stats_kernel<<<N_ROWS, 256, 0, stream>>>(pred, targ, wpear, wderiv, wpeak);
    fft_kernel<<<2 * N_ROWS, 256, 65536, stream>>>(pred, targ, fout);
    reduce_kernel<<<1, 256, 0, stream>>>(wpear, wderiv, wpeak, fout, (float*)d_out);
}

// Round 4
// 186.015 us; speedup vs baseline: 2.1400x; 1.0973x over previous
//
#include <hip/hip_runtime.h>
#include <hip/hip_bf16.h>
#include <math.h>

#define N_T    16384
#define N_ROWS 2048
#define M_FFT  8192
#define K_LO   410
#define K_HI   1365

__device__ __forceinline__ int rev13(int k) { return (int)(__brev((unsigned)k) >> 19); }
__device__ __forceinline__ float2 cmul(float2 a, float2 b) {
    return make_float2(a.x * b.x - a.y * b.y, a.x * b.y + a.y * b.x);
}
__device__ __forceinline__ int swz(int i) { return i ^ (((i >> 8) & 7) << 1); }

// One workgroup per (row, array). 8192-pt complex FFT: 5 register stages,
// swizzled LDS transpose, 5 register stages, 3 shfl stages, band argmax.
__global__ __launch_bounds__(256) void fft_kernel(const float* __restrict__ pred,
                                                  const float* __restrict__ targ,
                                                  float* __restrict__ fout) {
    extern __shared__ float2 z[];  // 8192 float2 = 64 KB
    const int wg = blockIdx.x;
    const int row = wg >> 1, arr = wg & 1;
    const float2* __restrict__ x = (const float2*)((arr ? targ : pred) + (size_t)row * N_T);
    const int t = threadIdx.x;

    float2 r[32];
#pragma unroll
    for (int m = 0; m < 32; ++m) r[m] = x[t + 256 * m];

    // ---- phase 1: DIF stages h = 4096,2048,1024,512,256 (register-internal) ----
#pragma unroll
    for (int p = 0; p < 5; ++p) {
        const int d = 16 >> p;  // partner offset in register index; h = 256*d
        float s0, c0, ss, cs;
        __sincosf((float)M_PI * (float)t / (float)(256 * d), &s0, &c0);
        __sincosf((float)M_PI / (float)d, &ss, &cs);
        const float2 wbase = make_float2(c0, -s0);
        const float2 wstep = make_float2(cs, -ss);
        float2 cw = wbase;
#pragma unroll
        for (int m = 0; m < 32; ++m) {
            if ((m & d) == 0) {
                float2 a = r[m], bq = r[m + d];
                r[m] = make_float2(a.x + bq.x, a.y + bq.y);
                float2 df = make_float2(a.x - bq.x, a.y - bq.y);
                r[m + d] = cmul(df, cw);
                if ((m & (d - 1)) == (d - 1)) cw = wbase;   // group wrap
                else cw = cmul(cw, wstep);
            }
        }
    }

    // ---- transpose via LDS: (t + 256m) -> (256b + c + 8w), b=t>>3, c=t&7 ----
#pragma unroll
    for (int m = 0; m < 32; ++m) {
        int i = t + 256 * m;
        z[swz(i)] = r[m];
    }
    __syncthreads();
    const int bb = t >> 3, cc = t & 7;
#pragma unroll
    for (int w = 0; w < 32; ++w) {
        int i = 256 * bb + cc + 8 * w;
        r[w] = z[swz(i)];
    }

    // ---- phase 2: DIF stages h = 128,64,32,16,8 (register-internal) ----
#pragma unroll
    for (int p = 0; p < 5; ++p) {
        const int d = 16 >> p;  // h = 8*d
        float s0, c0, ss, cs;
        __sincosf((float)M_PI * (float)cc / (float)(8 * d), &s0, &c0);
        __sincosf((float)M_PI / (float)d, &ss, &cs);
        const float2 wbase = make_float2(c0, -s0);
        const float2 wstep = make_float2(cs, -ss);
        float2 cw = wbase;
#pragma unroll
        for (int w = 0; w < 32; ++w) {
            if ((w & d) == 0) {
                float2 a = r[w], bq = r[w + d];
                r[w] = make_float2(a.x + bq.x, a.y + bq.y);
                float2 df = make_float2(a.x - bq.x, a.y - bq.y);
                r[w + d] = cmul(df, cw);
                if ((w & (d - 1)) == (d - 1)) cw = wbase;
                else cw = cmul(cw, wstep);
            }
        }
    }

    // ---- phase 3: DIF stages h = 4,2,1 via shfl_xor across c ----
    {   // h=4: twiddle e^{-i*pi*(c&3)/4} on upper half (c&4)
        float s1, c1;
        __sincosf((float)M_PI * (float)(cc & 3) * 0.25f, &s1, &c1);
        const float2 w4 = make_float2(c1, -s1);
        const bool up = (cc & 4) != 0;
#pragma unroll
        for (int w = 0; w < 32; ++w) {
            float ox = __shfl_xor(r[w].x, 4);
            float oy = __shfl_xor(r[w].y, 4);
            if (!up) { r[w].x += ox; r[w].y += oy; }
            else {
                float2 df = make_float2(ox - r[w].x, oy - r[w].y);
                r[w] = cmul(df, w4);
            }
        }
    }
    {   // h=2: twiddle {1,-i} by c&1 on upper half (c&2)
        const bool up = (cc & 2) != 0;
        const bool j1 = (cc & 1) != 0;
#pragma unroll
        for (int w = 0; w < 32; ++w) {
            float ox = __shfl_xor(r[w].x, 2);
            float oy = __shfl_xor(r[w].y, 2);
            if (!up) { r[w].x += ox; r[w].y += oy; }
            else {
                float dx = ox - r[w].x, dy = oy - r[w].y;
                r[w] = j1 ? make_float2(dy, -dx) : make_float2(dx, dy);
            }
        }
    }
    {   // h=1: no twiddle
        const bool up = (cc & 1) != 0;
#pragma unroll
        for (int w = 0; w < 32; ++w) {
            float ox = __shfl_xor(r[w].x, 1);
            float oy = __shfl_xor(r[w].y, 1);
            if (!up) { r[w].x += ox; r[w].y += oy; }
            else { r[w] = make_float2(ox - r[w].x, oy - r[w].y); }
        }
    }

    // ---- final store (bit-reversed-content array in natural position order) ----
    __syncthreads();  // all transpose reads done before overwrite
#pragma unroll
    for (int w = 0; w < 32; ++w) {
        int i = 256 * bb + cc + 8 * w;
        z[swz(i)] = r[w];
    }
    __syncthreads();

    // ---- combine to rfft bins in band, argmax (tie -> lowest k) ----
    float bestp = -1.0f;
    int bestk = 1 << 30;
    for (int k = K_LO + t; k <= K_HI; k += 256) {
        float2 A = z[swz(rev13(k))];
        float2 B = z[swz(rev13(M_FFT - k))];
        float Er = 0.5f * (A.x + B.x), Ei = 0.5f * (A.y - B.y);
        float Or = 0.5f * (A.y + B.y), Oi = 0.5f * (B.x - A.x);
        float th = (float)(M_PI) * (float)k / 8192.0f;
        float sn, cs;
        sincosf(th, &sn, &cs);
        float Xr = Er + cs * Or + sn * Oi;
        float Xi = Ei + cs * Oi - sn * Or;
        float p = Xr * Xr + Xi * Xi;
        if (p > bestp) { bestp = p; bestk = k; }
    }
    for (int off = 1; off < 64; off <<= 1) {
        float op = __shfl_xor(bestp, off);
        int   ok = __shfl_xor(bestk, off);
        if (op > bestp || (op == bestp && ok < bestk)) { bestp = op; bestk = ok; }
    }
    __syncthreads();  // all z reads done; reuse z[0..3] for cross-wave reduce
    if ((t & 63) == 0) z[t >> 6] = make_float2(bestp, (float)bestk);
    __syncthreads();
    if (t == 0) {
        for (int wv = 0; wv < 4; ++wv) {
            float2 rr = z[wv];
            int ok = (int)rr.y;
            if (rr.x > bestp || (rr.x == bestp && ok < bestk)) { bestp = rr.x; bestk = ok; }
        }
        fout[arr * N_ROWS + row] = (float)bestk * (30.0f / 16384.0f);
    }
}

// Per-element stats body: identical math to the validated LDS version.
__device__ __forceinline__ void stat_elem(int i,
    float pm2, float pm1, float p0, float pp1, float pp2,
    float tm2, float tm1, float t0, float tp1, float tp2,
    float* acc) {
    acc[0] += p0; acc[1] += p0 * p0;
    acc[2] += t0; acc[3] += t0 * t0;
    acc[4] += p0 * t0;
    float g1p, g1t, g2p, g2t;
    if (i >= 2 && i <= N_T - 3) {
        g1p = 0.5f * (pp1 - pm1); g1t = 0.5f * (tp1 - tm1);
        g2p = 0.5f * (0.5f * (pp2 - p0) - 0.5f * (p0 - pm2));
        g2t = 0.5f * (0.5f * (tp2 - t0) - 0.5f * (t0 - tm2));
    } else if (i == 0) {
        g1p = pp1 - p0;              g2p = 0.5f * (pp2 - p0) - (pp1 - p0);
        g1t = tp1 - t0;              g2t = 0.5f * (tp2 - t0) - (tp1 - t0);
    } else if (i == 1) {
        g1p = 0.5f * (pp1 - pm1);    g2p = 0.5f * (0.5f * (pp2 - p0) - (p0 - pm1));
        g1t = 0.5f * (tp1 - tm1);    g2t = 0.5f * (0.5f * (tp2 - t0) - (t0 - tm1));
    } else if (i == N_T - 2) {
        g1p = 0.5f * (pp1 - pm1);    g2p = 0.5f * ((pp1 - p0) - 0.5f * (p0 - pm2));
        g1t = 0.5f * (tp1 - tm1);    g2t = 0.5f * ((tp1 - t0) - 0.5f * (t0 - tm2));
    } else {  // i == N_T-1
        g1p = p0 - pm1;              g2p = (p0 - pm1) - 0.5f * (p0 - pm2);
        g1t = t0 - tm1;              g2t = (t0 - tm1) - 0.5f * (t0 - tm2);
    }
    acc[5] += g1p * g1t; acc[6] += g1p * g1p; acc[7] += g1t * g1t;
    acc[8] += g2p * g2t; acc[9] += g2p * g2p; acc[10] += g2t * g2t;
    if (i >= 1 && i <= N_T - 2) {
        bool mx  = (p0 > pm1) && (p0 > pp1);
        bool mn  = (p0 < pm1) && (p0 < pp1);
        bool mxt = (t0 > tm1) && (t0 > tp1);
        bool mnt = (t0 < tm1) && (t0 < tp1);
        acc[11] += mx ? 1.0f : 0.0f;
        acc[12] += mn ? 1.0f : 0.0f;
        acc[13] += mxt ? 1.0f : 0.0f;
        acc[14] += mnt ? 1.0f : 0.0f;
        acc[15] += mx ? p0 : 0.0f;
        acc[16] += mn ? p0 : 0.0f;
    }
}

// One workgroup per row: pure streaming, no LDS staging. Thread owns 16
// float4 chunks; +-2 halo via aligned float2 loads that hit L1 (neighbor lines).
__global__ __launch_bounds__(256) void stats_kernel(const float* __restrict__ pred,
                                                    const float* __restrict__ targ,
                                                    float* __restrict__ wpear,
                                                    float* __restrict__ wderiv,
                                                    float* __restrict__ wpeak) {
    __shared__ float red[4][17];
    int row = blockIdx.x, tid = threadIdx.x;
    const float* p = pred + (size_t)row * N_T;
    const float* t = targ + (size_t)row * N_T;

    float acc[17];
#pragma unroll
    for (int q = 0; q < 17; ++q) acc[q] = 0.0f;

    for (int q = 0; q < 16; ++q) {
        int e0 = 4 * tid + 1024 * q;
        float4 Cp = *(const float4*)(p + e0);
        float4 Ct = *(const float4*)(t + e0);
        float2 Lp = make_float2(0.0f, 0.0f), Lt = make_float2(0.0f, 0.0f);
        float2 Rp = make_float2(0.0f, 0.0f), Rt = make_float2(0.0f, 0.0f);
        if (e0 > 0) {        // aligned: (e0-2)*4 bytes is 8B-aligned
            Lp = *(const float2*)(p + e0 - 2);
            Lt = *(const float2*)(t + e0 - 2);
        }
        if (e0 + 4 < N_T) {
            Rp = *(const float2*)(p + e0 + 4);
            Rt = *(const float2*)(t + e0 + 4);
        }
        stat_elem(e0 + 0, Lp.x, Lp.y, Cp.x, Cp.y, Cp.z,
                          Lt.x, Lt.y, Ct.x, Ct.y, Ct.z, acc);
        stat_elem(e0 + 1, Lp.y, Cp.x, Cp.y, Cp.z, Cp.w,
                          Lt.y, Ct.x, Ct.y, Ct.z, Ct.w, acc);
        stat_elem(e0 + 2, Cp.x, Cp.y, Cp.z, Cp.w, Rp.x,
                          Ct.x, Ct.y, Ct.z, Ct.w, Rt.x, acc);
        stat_elem(e0 + 3, Cp.y, Cp.z, Cp.w, Rp.x, Rp.y,
                          Ct.y, Ct.z, Ct.w, Rt.x, Rt.y, acc);
    }

    int lane = tid & 63, wv = tid >> 6;
#pragma unroll
    for (int q = 0; q < 17; ++q) {
        float v = acc[q];
        for (int off = 1; off < 64; off <<= 1) v += __shfl_xor(v, off);
        if (lane == 0) red[wv][q] = v;
    }
    __syncthreads();
    if (tid == 0) {
        float a[17];
#pragma unroll
        for (int q = 0; q < 17; ++q) a[q] = red[0][q] + red[1][q] + red[2][q] + red[3][q];
        const float Nf = (float)N_T;
        float cov = a[4] - a[0] * a[2] / Nf;
        float vp  = a[1] - a[0] * a[0] / Nf;
        float vt  = a[3] - a[2] * a[2] / Nf;
        float r   = cov / sqrtf(vp * vt);
        float c1  = a[5] / sqrtf(a[6] * a[7]);
        float c2  = a[8] / sqrtf(a[9] * a[10]);
        float cntd  = fabsf(a[13] - a[11]);
        float ncntd = fabsf(a[14] - a[12]);
        float vald  = fabsf(1.0f - a[15] / a[11]);
        float nvald = fabsf(1.0f - a[16] / a[12]);
        wpear[row]  = 1.0f - r;
        wderiv[row] = c1 + c2;
        wpeak[row]  = 0.5f * (cntd + ncntd + vald + nvald);
    }
}

__global__ __launch_bounds__(256) void reduce_kernel(const float* __restrict__ wpear,
                                                     const float* __restrict__ wderiv,
                                                     const float* __restrict__ wpeak,
                                                     const float* __restrict__ fout,
                                                     float* __restrict__ out) {
    __shared__ float red[4][3];
    int tid = threadIdx.x;
    float s1 = 0.0f, s2 = 0.0f, s3 = 0.0f;
    for (int r = tid; r < N_ROWS; r += 256) {
        s1 += wpear[r];
        s2 += wderiv[r];
        s3 += wpeak[r] + fabsf(fout[N_ROWS + r] - fout[r]);
    }
    int lane = tid & 63, wv = tid >> 6;
    for (int off = 1; off < 64; off <<= 1) {
        s1 += __shfl_xor(s1, off);
        s2 += __shfl_xor(s2, off);
        s3 += __shfl_xor(s3, off);
    }
    if (lane == 0) { red[wv][0] = s1; red[wv][1] = s2; red[wv][2] = s3; }
    __syncthreads();
    if (tid == 0) {
        float a = 0.0f, b = 0.0f, c = 0.0f;
        for (int w = 0; w < 4; ++w) { a += red[w][0]; b += red[w][1]; c += red[w][2]; }
        const float Nf = (float)N_ROWS;
        float res = a / Nf + c / Nf + (2.0f - b / Nf);
        out[0] = res;  // reference output dtype is float32
    }
}

extern "C" void kernel_launch(void* const* d_in, const int* in_sizes, int n_in,
                              void* d_out, int out_size, void* d_ws, size_t ws_size,
                              hipStream_t stream) {
    const float* pred = (const float*)d_in[0];
    const float* targ = (const float*)d_in[1];
    float* ws = (float*)d_ws;
    float* wpear  = ws;             // 2048
    float* wderiv = ws + 2048;      // 2048
    float* wpeak  = ws + 4096;      // 2048
    float* fout   = ws + 6144;      // 4096 (pred freqs, then targ freqs)

    stats_kernel<<<N_ROWS, 256, 0, stream>>>(pred, targ, wpear, wderiv, wpeak);
    fft_kernel<<<2 * N_ROWS, 256, 65536, stream>>>(pred, targ, fout);
    reduce_kernel<<<1, 256, 0, stream>>>(wpear, wderiv, wpeak, fout, (float*)d_out);
}